// Round 5
// baseline (724.078 us; speedup 1.0000x reference)
//
#include <hip/hip_runtime.h>

// ---------------- dims ----------------
constexpr int HH    = 64;     // heads
constexpr int PP    = 64;     // head dim
constexpr int HID   = 2048;
constexpr int NST   = 128;    // state dim
constexpr int LCC   = 256;    // chunk len
constexpr int INTER = 4096;
constexpr int CONVD = 4352;
constexpr int PROJD = 8512;
constexpr int BB    = 4;
constexpr int SS    = 1024;
constexpr int NC    = 4;      // chunks
constexpr int MR    = BB * SS;      // 4096 rows
constexpr int NPAD1 = 8704;         // PROJD padded to 256

constexpr int SLOT_A = 128 * 64;    // u16 per A K-tile slot (16KB)
constexpr int SLOT_B = 256 * 64;    // u16 per B K-tile slot (32KB)
constexpr int GLDS   = 3 * (SLOT_A + SLOT_B) * 2;  // 147456 B

typedef unsigned short u16;
typedef __bf16 bf16x8_t __attribute__((ext_vector_type(8)));
typedef short short8 __attribute__((ext_vector_type(8)));
typedef float f32x4 __attribute__((ext_vector_type(4)));
typedef u16 u16x4 __attribute__((ext_vector_type(4)));

__device__ __forceinline__ float bf2f(u16 u) {
  union { unsigned int i; float f; } v; v.i = ((unsigned int)u) << 16; return v.f;
}
__device__ __forceinline__ u16 f2bf(float f) {
  union { float f; unsigned int i; } v; v.f = f;
  unsigned int r = v.i + 0x7FFFu + ((v.i >> 16) & 1u);
  return (u16)(r >> 16);
}
__device__ __forceinline__ f32x4 mfma16(short8 a, short8 b, f32x4 c) {
  union U { short8 s; bf16x8_t b; };
  U ua; ua.s = a; U ub; ub.s = b;
  return __builtin_amdgcn_mfma_f32_16x16x32_bf16(ua.b, ub.b, c, 0, 0, 0);
}
__device__ __forceinline__ float sigm(float x) { return 1.f / (1.f + __expf(-x)); }
__device__ __forceinline__ void gload16(const u16* g, u16* l) {
  __builtin_amdgcn_global_load_lds(
      (const __attribute__((address_space(1))) void*)g,
      (__attribute__((address_space(3))) void*)l, 16, 0, 0);
}

// ---------------- fp32 -> bf16 convert (hs) ------------------------------------
__global__ void f32_to_bf16(const float* __restrict__ in, u16* __restrict__ out) {
  int i = (blockIdx.x * 256 + threadIdx.x) * 8;
  float4 a = *(const float4*)&in[i];
  float4 b = *(const float4*)&in[i + 4];
  short8 v;
  v[0] = (short)f2bf(a.x); v[1] = (short)f2bf(a.y);
  v[2] = (short)f2bf(a.z); v[3] = (short)f2bf(a.w);
  v[4] = (short)f2bf(b.x); v[5] = (short)f2bf(b.y);
  v[6] = (short)f2bf(b.z); v[7] = (short)f2bf(b.w);
  *(short8*)&out[i] = v;
}

// ---------------- transpose f32 -> bf16 (weights), zero-pad extra out rows -----
__global__ void transpose_w(const float* __restrict__ in, u16* __restrict__ out,
                            int K_, int N_) {
  __shared__ float tile[32][33];
  int k0 = blockIdx.y * 32, n0 = blockIdx.x * 32, t = threadIdx.x;
#pragma unroll
  for (int i = 0; i < 4; ++i) {
    int flat = i * 256 + t; int kk = flat >> 5, nn = flat & 31;
    int n = n0 + nn;
    tile[kk][nn] = (n < N_) ? in[(size_t)(k0 + kk) * N_ + n] : 0.f;
  }
  __syncthreads();
#pragma unroll
  for (int i = 0; i < 4; ++i) {
    int flat = i * 256 + t; int nn = flat >> 5, kk = flat & 31;
    out[(size_t)(n0 + nn) * K_ + k0 + kk] = f2bf(tile[kk][nn]);
  }
}

// ---------------- generic bf16 transpose, batched: in [R][C] -> out [C][R] -----
__global__ void transpose_bf16(const u16* __restrict__ in, u16* __restrict__ out,
                               int R, int C) {
  int bt = blockIdx.z;
  const u16* ip = in + (size_t)bt * R * C;
  u16* op = out + (size_t)bt * R * C;
  __shared__ u16 tile[32][33];
  int r0 = blockIdx.y * 32, c0 = blockIdx.x * 32, t = threadIdx.x;
#pragma unroll
  for (int i = 0; i < 4; ++i) {
    int flat = i * 256 + t; int rr = flat >> 5, cc = flat & 31;
    tile[rr][cc] = ip[(size_t)(r0 + rr) * C + c0 + cc];
  }
  __syncthreads();
#pragma unroll
  for (int i = 0; i < 4; ++i) {
    int flat = i * 256 + t; int cc = flat >> 5, rr = flat & 31;
    op[(size_t)(c0 + cc) * R + r0 + rr] = tile[rr][cc];
  }
}

// ---------------- GEMM: 128x256 tile, BK=64, 3-deep counted-vmcnt pipeline -----
// 4 waves (1M x 4N), per-wave 128x64 output; global_load_lds w16; T2 XOR swizzle.
// MODE 0: out fp32 (GEMM2).  MODE 1: split bf16 out (GEMM1).
template <int MODE>
__global__ __launch_bounds__(256, 1) void gemm_bt(
    const u16* __restrict__ A, const u16* __restrict__ Bt,
    const float* __restrict__ bias, void* __restrict__ Cp,
    u16* __restrict__ hbcb, u16* __restrict__ dtsec,
    int M, int Nreal, int K, int gx) {
  extern __shared__ u16 smem[];
  u16* As = smem;                     // [3][128*64]
  u16* Bs = smem + 3 * SLOT_A;        // [3][256*64]
  // bijective XCD swizzle (gridDim.x % 8 == 0)
  const int nwg = gridDim.x, bid = blockIdx.x;
  const int q = nwg >> 3;
  const int swz = (bid & 7) * q + (bid >> 3);
  const int bx = swz % gx, by = swz / gx;
  const int m0 = by * 128, n0 = bx * 256;
  const int t = threadIdx.x;
  const int w = t >> 6, lane = t & 63, lr = lane & 15, lhi = lane >> 4;
  const int srow = t >> 3;                                 // 0..31
  const int sw_scol = (((t & 7) ^ ((t >> 3) & 7)) << 3);   // pre-swizzled src col
  const u16* ga = A + (size_t)(m0 + srow) * K + sw_scol;
  const u16* gb = Bt + (size_t)(n0 + srow) * K + sw_scol;
  const int swz_rd = (lr & 7) << 3;                        // read-side XOR
  const int NT = K >> 6;
  u16* lwa = As + w * 512;   // wave-uniform LDS bases (8 rows * 64 * u16)
  u16* lwb = Bs + w * 512;

#define STAGE_T(ts, sl)                                                        \
  {                                                                            \
    const u16* gk = ga + (size_t)(ts)*64;                                      \
    u16* ld = lwa + (sl)*SLOT_A;                                               \
    _Pragma("unroll") for (int i = 0; i < 4; ++i)                              \
        gload16(gk + (size_t)(i * 32) * K, ld + i * 2048);                     \
    const u16* gk2 = gb + (size_t)(ts)*64;                                     \
    u16* ld2 = lwb + (sl)*SLOT_B;                                              \
    _Pragma("unroll") for (int i = 0; i < 8; ++i)                              \
        gload16(gk2 + (size_t)(i * 32) * K, ld2 + i * 2048);                   \
  }

  // prologue: tiles 0,1 -> slots 0,1 (24 loads); drain oldest 12 (tile 0)
  STAGE_T(0, 0);
  STAGE_T(1, 1);
  asm volatile("s_waitcnt vmcnt(12)" ::: "memory");
  __builtin_amdgcn_s_barrier();
  __builtin_amdgcn_sched_barrier(0);

  f32x4 acc[8][4] = {};
  int sl = 0;
  for (int tt = 0; tt < NT; ++tt) {
    const int ts = (tt + 2 < NT) ? tt + 2 : NT - 1;    // clamped prefetch
    const int sn = (sl >= 1) ? sl - 1 : sl + 2;        // (sl+2)%3
    STAGE_T(ts, sn);
    const u16* as = As + sl * SLOT_A;
    const u16* bs = Bs + sl * SLOT_B;
    short8 af[8][2], bfv[4][2];
#pragma unroll
    for (int ks = 0; ks < 2; ++ks) {
      const int cs = (ks * 32 + lhi * 8) ^ swz_rd;
#pragma unroll
      for (int mi = 0; mi < 8; ++mi)
        af[mi][ks] = *(const short8*)&as[(mi * 16 + lr) * 64 + cs];
#pragma unroll
      for (int ni = 0; ni < 4; ++ni)
        bfv[ni][ks] = *(const short8*)&bs[(w * 64 + ni * 16 + lr) * 64 + cs];
    }
    __builtin_amdgcn_s_setprio(1);
#pragma unroll
    for (int ks = 0; ks < 2; ++ks)
#pragma unroll
      for (int mi = 0; mi < 8; ++mi)
#pragma unroll
        for (int ni = 0; ni < 4; ++ni)
          acc[mi][ni] = mfma16(af[mi][ks], bfv[ni][ks], acc[mi][ni]);
    __builtin_amdgcn_s_setprio(0);
    asm volatile("s_waitcnt vmcnt(12)" ::: "memory");  // drain tile tt+1 only
    __builtin_amdgcn_s_barrier();
    __builtin_amdgcn_sched_barrier(0);
    sl = (sl < 2) ? sl + 1 : 0;
  }
#undef STAGE_T

#pragma unroll
  for (int ni = 0; ni < 4; ++ni) {
    int col = n0 + w * 64 + ni * 16 + lr;
    if (col >= Nreal) continue;
    float bv = bias[col];
#pragma unroll
    for (int mi = 0; mi < 8; ++mi)
#pragma unroll
      for (int j = 0; j < 4; ++j) {
        int row = m0 + mi * 16 + lhi * 4 + j;
        float v = acc[mi][ni][j] + bv;
        if (MODE == 0) {
          ((float*)Cp)[(size_t)row * Nreal + col] = v;
        } else {
          u16 o = f2bf(v);
          if (col < INTER)              ((u16*)Cp)[(size_t)row * INTER + col] = o;
          else if (col < INTER + CONVD) hbcb[(size_t)row * CONVD + (col - INTER)] = o;
          else                          dtsec[(size_t)row * HH + (col - INTER - CONVD)] = o;
        }
      }
  }
}

// ---------------- conv1d (K=4, causal) + SiLU + split, x8 vectorized -----------
__global__ __launch_bounds__(256) void conv_silu(
    const u16* __restrict__ hbcb, const float* __restrict__ convw,
    u16* __restrict__ X_lp, u16* __restrict__ Bc, u16* __restrict__ Cc) {
  int idx = blockIdx.x * 256 + threadIdx.x;  // < BB*SS*(CONVD/8)
  int c8 = idx % (CONVD / 8);
  int rest = idx / (CONVD / 8);
  int s = rest & (SS - 1);
  int b = rest >> 10;
  int ch = c8 * 8;
  short8 v[4];
#pragma unroll
  for (int k = 0; k < 4; ++k) {
    int ss = s - 3 + k;
    if (ss >= 0) v[k] = *(const short8*)&hbcb[(size_t)(b * SS + ss) * CONVD + ch];
    else         v[k] = short8{0, 0, 0, 0, 0, 0, 0, 0};
  }
  short8 o;
#pragma unroll
  for (int j = 0; j < 8; ++j) {
    float4 wj = *(const float4*)&convw[(ch + j) * 4];
    float a = bf2f((u16)v[0][j]) * wj.x + bf2f((u16)v[1][j]) * wj.y +
              bf2f((u16)v[2][j]) * wj.z + bf2f((u16)v[3][j]) * wj.w;
    o[j] = (short)f2bf(a * sigm(a));
  }
  if (ch < INTER)
    *(short8*)&X_lp[((size_t)(b * HH + (ch >> 6)) * SS + s) * PP + (ch & 63)] = o;
  else if (ch < INTER + NST)
    *(short8*)&Bc[((size_t)(b * SS + s)) * NST + (ch - INTER)] = o;
  else
    *(short8*)&Cc[((size_t)(b * SS + s)) * NST + (ch - INTER - NST)] = o;
}

// ---------------- dt: softplus(dt+bias) -> dtv [bh][s] -------------------------
__global__ void dtk(const u16* __restrict__ dtsec, const float* __restrict__ dtb,
                    const float* __restrict__ alog, float* __restrict__ dtv) {
  int idx = blockIdx.x * 256 + threadIdx.x;  // < BB*SS*HH
  int hh = idx & 63;
  int s = (idx >> 6) & (SS - 1);
  int b = idx >> 16;
  float x = bf2f(dtsec[(size_t)(b * SS + s) * HH + hh]) + dtb[hh];
  float sp = (x > 20.f) ? x : log1pf(__expf(x));
  dtv[(size_t)(b * HH + hh) * SS + s] = sp;
}

// ---------------- per-chunk inclusive cumsum of -exp(A_log)*dt (wave scan) -----
__global__ __launch_bounds__(256) void cumsum_scan(
    const float* __restrict__ dtv, const float* __restrict__ alog,
    float* __restrict__ cumA) {
  const int bh = blockIdx.x;
  const int h = bh & 63;
  const int t = threadIdx.x, w = t >> 6, lane = t & 63;
  const float na = -__expf(alog[h]);
  size_t base = (size_t)bh * SS + w * LCC;
  float4 v = *(const float4*)&dtv[base + lane * 4];
  float a0 = na * v.x;
  float s1 = a0 + na * v.y;
  float s2 = s1 + na * v.z;
  float tot = s2 + na * v.w;
  float run = tot;
#pragma unroll
  for (int off = 1; off < 64; off <<= 1) {
    float u = __shfl_up(run, off);
    if (lane >= off) run += u;
  }
  float excl = run - tot;
  float4 o; o.x = excl + a0; o.y = excl + s1; o.z = excl + s2; o.w = excl + tot;
  *(float4*)&cumA[base + lane * 4] = o;
}

// ---------------- SSD pass 1: Y_diag + chunk states ----------------------------
__global__ __launch_bounds__(256) void ssd1(
    const u16* __restrict__ Cc, const u16* __restrict__ Bc,
    const u16* __restrict__ Btc, const u16* __restrict__ Xt,
    const float* __restrict__ cumA, const float* __restrict__ dtv,
    u16* __restrict__ ybb, u16* __restrict__ statesb) {
  const int h = blockIdx.x, c = blockIdx.y, b = blockIdx.z;
  const int bh = b * HH + h, s0 = c * LCC;
  const int t = threadIdx.x, w = t >> 6, lane = t & 63, lr = lane & 15, lhi = lane >> 4;
  __shared__ float cumA_s[LCC], dtv_s[LCC], w_s[LCC];
  __shared__ __align__(16) u16 Mld[4][64 * 72];
  cumA_s[t] = cumA[(size_t)bh * SS + s0 + t];
  dtv_s[t] = dtv[(size_t)bh * SS + s0 + t];
  __syncthreads();
  w_s[t] = dtv_s[t] * __expf(cumA_s[LCC - 1] - cumA_s[t]);
  __syncthreads();

  f32x4 Yacc[4][4] = {};
  u16* Mw = &Mld[w][0];
  for (int st = 0; st <= w; ++st) {
    f32x4 G[4][4] = {};
#pragma unroll
    for (int ks = 0; ks < 4; ++ks) {
      short8 cf[4], bfr[4];
#pragma unroll
      for (int mi = 0; mi < 4; ++mi)
        cf[mi] = *(const short8*)&Cc[((size_t)(b * SS + s0 + w * 64 + mi * 16 + lr)) * NST + ks * 32 + lhi * 8];
#pragma unroll
      for (int ni = 0; ni < 4; ++ni)
        bfr[ni] = *(const short8*)&Bc[((size_t)(b * SS + s0 + st * 64 + ni * 16 + lr)) * NST + ks * 32 + lhi * 8];
#pragma unroll
      for (int mi = 0; mi < 4; ++mi)
#pragma unroll
        for (int ni = 0; ni < 4; ++ni)
          G[mi][ni] = mfma16(cf[mi], bfr[ni], G[mi][ni]);
    }
#pragma unroll
    for (int mi = 0; mi < 4; ++mi)
#pragma unroll
      for (int ni = 0; ni < 4; ++ni) {
        int sloc = st * 64 + ni * 16 + lr;
        float ds = dtv_s[sloc];
#pragma unroll
        for (int j = 0; j < 4; ++j) {
          int l = w * 64 + mi * 16 + lhi * 4 + j;
          float v = (sloc <= l) ? G[mi][ni][j] * __expf(cumA_s[l] - cumA_s[sloc]) * ds : 0.f;
          Mw[(mi * 16 + lhi * 4 + j) * 72 + ni * 16 + lr] = f2bf(v);
        }
      }
#pragma unroll
    for (int kh = 0; kh < 2; ++kh) {
      short8 xf[4];
#pragma unroll
      for (int ni = 0; ni < 4; ++ni)
        xf[ni] = *(const short8*)&Xt[((size_t)bh * PP + ni * 16 + lr) * SS + s0 + st * 64 + kh * 32 + lhi * 8];
#pragma unroll
      for (int mi = 0; mi < 4; ++mi) {
        short8 mf = *(const short8*)&Mw[(mi * 16 + lr) * 72 + kh * 32 + lhi * 8];
#pragma unroll
        for (int ni = 0; ni < 4; ++ni)
          Yacc[mi][ni] = mfma16(mf, xf[ni], Yacc[mi][ni]);
      }
    }
  }
#pragma unroll
  for (int mi = 0; mi < 4; ++mi)
#pragma unroll
    for (int ni = 0; ni < 4; ++ni)
#pragma unroll
      for (int j = 0; j < 4; ++j) {
        int l = w * 64 + mi * 16 + lhi * 4 + j;
        int p = ni * 16 + lr;
        ybb[((size_t)(b * SS + s0 + l)) * INTER + h * PP + p] = f2bf(Yacc[mi][ni][j]);
      }
  f32x4 Sacc[4][2] = {};
  for (int ks = 0; ks < 8; ++ks) {
    f32x4 w0 = *(const f32x4*)&w_s[ks * 32 + lhi * 8];
    f32x4 w1 = *(const f32x4*)&w_s[ks * 32 + lhi * 8 + 4];
    short8 bfr[2];
#pragma unroll
    for (int nj = 0; nj < 2; ++nj) {
      short8 br = *(const short8*)&Btc[((size_t)b * NST + w * 32 + nj * 16 + lr) * SS + s0 + ks * 32 + lhi * 8];
      short8 bs;
      bs[0] = (short)f2bf(bf2f((u16)br[0]) * w0[0]);
      bs[1] = (short)f2bf(bf2f((u16)br[1]) * w0[1]);
      bs[2] = (short)f2bf(bf2f((u16)br[2]) * w0[2]);
      bs[3] = (short)f2bf(bf2f((u16)br[3]) * w0[3]);
      bs[4] = (short)f2bf(bf2f((u16)br[4]) * w1[0]);
      bs[5] = (short)f2bf(bf2f((u16)br[5]) * w1[1]);
      bs[6] = (short)f2bf(bf2f((u16)br[6]) * w1[2]);
      bs[7] = (short)f2bf(bf2f((u16)br[7]) * w1[3]);
      bfr[nj] = bs;
    }
#pragma unroll
    for (int mi = 0; mi < 4; ++mi) {
      short8 af = *(const short8*)&Xt[((size_t)bh * PP + mi * 16 + lr) * SS + s0 + ks * 32 + lhi * 8];
#pragma unroll
      for (int nj = 0; nj < 2; ++nj)
        Sacc[mi][nj] = mfma16(af, bfr[nj], Sacc[mi][nj]);
    }
  }
#pragma unroll
  for (int mi = 0; mi < 4; ++mi)
#pragma unroll
    for (int nj = 0; nj < 2; ++nj)
#pragma unroll
      for (int j = 0; j < 4; ++j) {
        int p = mi * 16 + lhi * 4 + j;
        int n = w * 32 + nj * 16 + lr;
        statesb[((((size_t)b * NC + c) * HH + h) * PP + p) * NST + n] = f2bf(Sacc[mi][nj][j]);
      }
}

// ---------------- inter-chunk recurrence (IN PLACE: states -> prev) ------------
__global__ void reck(u16* __restrict__ statesb, const float* __restrict__ cumA) {
  int idx = blockIdx.x * 256 + threadIdx.x;  // < BB*HH*PP*NST
  int n = idx & 127, p = (idx >> 7) & 63, bh = idx >> 13;
  int b = bh >> 6, h = bh & 63;
  float prev = 0.f;
#pragma unroll
  for (int c2 = 0; c2 < NC; ++c2) {
    size_t si = ((((size_t)b * NC + c2) * HH + h) * PP + p) * NST + n;
    float s = bf2f(statesb[si]);           // read BEFORE overwrite
    statesb[si] = f2bf(prev);
    float tot = cumA[(size_t)bh * SS + c2 * LCC + (LCC - 1)];
    prev = prev * __expf(tot) + s;
  }
}

// ---------------- SSD pass 2: Y_off + D residual (y in bf16, RMW) --------------
__global__ __launch_bounds__(256) void ssd2(
    const u16* __restrict__ Cc, const u16* __restrict__ prevb,
    const u16* __restrict__ X_lp, const float* __restrict__ cumA,
    const float* __restrict__ Dv, u16* __restrict__ ybb) {
  const int h = blockIdx.x, c = blockIdx.y, b = blockIdx.z;
  const int bh = b * HH + h, s0 = c * LCC;
  const int t = threadIdx.x, w = t >> 6, lane = t & 63, lr = lane & 15, lhi = lane >> 4;
  __shared__ float cumA_s[LCC];
  cumA_s[t] = cumA[(size_t)bh * SS + s0 + t];
  __syncthreads();
  f32x4 acc[4][4] = {};
  const size_t stbase = (((size_t)b * NC + c) * HH + h) * PP;
#pragma unroll
  for (int ks = 0; ks < 4; ++ks) {
    short8 sf[4];
#pragma unroll
    for (int pj = 0; pj < 4; ++pj)
      sf[pj] = *(const short8*)&prevb[(stbase + pj * 16 + lr) * NST + ks * 32 + lhi * 8];
#pragma unroll
    for (int mi = 0; mi < 4; ++mi) {
      short8 cf = *(const short8*)&Cc[((size_t)(b * SS + s0 + w * 64 + mi * 16 + lr)) * NST + ks * 32 + lhi * 8];
#pragma unroll
      for (int pj = 0; pj < 4; ++pj)
        acc[mi][pj] = mfma16(cf, sf[pj], acc[mi][pj]);
    }
  }
  float Dh = Dv[h];
#pragma unroll
  for (int mi = 0; mi < 4; ++mi)
#pragma unroll
    for (int pj = 0; pj < 4; ++pj)
#pragma unroll
      for (int j = 0; j < 4; ++j) {
        int l = w * 64 + mi * 16 + lhi * 4 + j;
        int p = pj * 16 + lr;
        size_t yi = ((size_t)(b * SS + s0 + l)) * INTER + h * PP + p;
        float xv = bf2f(X_lp[((size_t)bh * SS + s0 + l) * PP + p]);
        float cur = bf2f(ybb[yi]);
        ybb[yi] = f2bf(cur + acc[mi][pj][j] * __expf(cumA_s[l]) + Dh * xv);
      }
}

// ---------------- gate (SiLU) + RMSNorm -> bf16 --------------------------------
__global__ __launch_bounds__(256) void gatenorm(
    const u16* __restrict__ ybb, const u16* __restrict__ gateb,
    const float* __restrict__ nw, u16* __restrict__ xgn) {
  const int r = blockIdx.x, t = threadIdx.x;
  const int w = t >> 6, lane = t & 63;
  float xg[16];
  float s2 = 0.f;
#pragma unroll
  for (int i = 0; i < 2; ++i) {
    int col = (i * 256 + t) * 8;
    short8 yv = *(const short8*)&ybb[(size_t)r * INTER + col];
    short8 gv = *(const short8*)&gateb[(size_t)r * INTER + col];
#pragma unroll
    for (int j = 0; j < 8; ++j) {
      float g = bf2f((u16)gv[j]);
      float o = bf2f((u16)yv[j]) * g * sigm(g);
      xg[i * 8 + j] = o;
      s2 += o * o;
    }
  }
#pragma unroll
  for (int off = 32; off > 0; off >>= 1) s2 += __shfl_down(s2, off);
  __shared__ float red[4];
  if (lane == 0) red[w] = s2;
  __syncthreads();
  float rstd = rsqrtf((red[0] + red[1] + red[2] + red[3]) * (1.f / INTER) + 1e-5f);
#pragma unroll
  for (int i = 0; i < 2; ++i) {
    int col = (i * 256 + t) * 8;
    short8 o;
#pragma unroll
    for (int j = 0; j < 8; ++j)
      o[j] = (short)f2bf(xg[i * 8 + j] * rstd * nw[col + j]);
    *(short8*)&xgn[(size_t)r * INTER + col] = o;
  }
}

// ---------------- launch -------------------------------------------------------
extern "C" void kernel_launch(void* const* d_in, const int* in_sizes, int n_in,
                              void* d_out, int out_size, void* d_ws, size_t ws_size,
                              hipStream_t stream) {
  const float* hs   = (const float*)d_in[0];
  const float* w1   = (const float*)d_in[1];
  const float* b1   = (const float*)d_in[2];
  const float* cw   = (const float*)d_in[3];
  const float* dtb  = (const float*)d_in[4];
  const float* alog = (const float*)d_in[5];
  const float* Dv   = (const float*)d_in[6];
  const float* nw   = (const float*)d_in[7];
  const float* w2   = (const float*)d_in[8];
  const float* b2   = (const float*)d_in[9];
  float* out = (float*)d_out;

  char* ws = (char*)d_ws;
  size_t off = 0;
  auto alloc = [&](size_t bytes) -> char* {
    char* p = ws + off;
    off += (bytes + 255) & ~(size_t)255;
    return p;
  };
  // region A: W1t (35.7MB) -> Xt (33.6MB) after GEMM1
  char* regA = alloc((size_t)NPAD1 * HID * 2);
  u16* W1t = (u16*)regA;
  u16* Xt  = (u16*)regA;
  // region B: gate (bf16) [GEMM1 .. gatenorm]
  u16* gateb = (u16*)alloc((size_t)MR * INTER * 2);
  // region C: hbc (35.7MB) -> y bf16 (33.6MB) after conv
  char* regC = alloc((size_t)MR * CONVD * 2);
  u16* hbcb = (u16*)regC;
  u16* ybb  = (u16*)regC;
  // region D: X_lp -> xgn after ssd2
  char* regD = alloc((size_t)BB * HH * SS * PP * 2);
  u16* X_lp = (u16*)regD;
  u16* xgn  = (u16*)regD;
  // region E: states bf16 (in-place -> prev) -> W2t after ssd2
  char* regE = alloc((size_t)BB * NC * HH * PP * NST * 2);
  u16* statesb = (u16*)regE;
  u16* W2t     = (u16*)regE;
  // small buffers
  u16*   hs16  = (u16*)alloc((size_t)MR * HID * 2);
  u16*   dtsec = (u16*)alloc((size_t)MR * HH * 2);
  u16*   Bc    = (u16*)alloc((size_t)BB * SS * NST * 2);
  u16*   Cc    = (u16*)alloc((size_t)BB * SS * NST * 2);
  u16*   Btc   = (u16*)alloc((size_t)BB * NST * SS * 2);
  float* dtv   = (float*)alloc((size_t)BB * HH * SS * 4);
  float* cumA  = (float*)alloc((size_t)BB * HH * SS * 4);

  if (off > ws_size) return;  // graceful fail -> diagnostic absmax

  // allow 144KB dynamic LDS on the GEMM kernels (idempotent, host-side)
  hipFuncSetAttribute((const void*)gemm_bt<1>,
                      hipFuncAttributeMaxDynamicSharedMemorySize, GLDS);
  hipFuncSetAttribute((const void*)gemm_bt<0>,
                      hipFuncAttributeMaxDynamicSharedMemorySize, GLDS);

  // hs fp32 -> bf16
  f32_to_bf16<<<(MR * HID) / (256 * 8), 256, 0, stream>>>(hs, hs16);
  // W1 transpose (fp32 -> bf16, padded rows zeroed)
  transpose_w<<<dim3(NPAD1 / 32, HID / 32), 256, 0, stream>>>(w1, W1t, HID, PROJD);
  // GEMM1: grid 32x34 = 1088 (%8==0), split epilogue -> gateb / hbcb / dtsec
  gemm_bt<1><<<1088, 256, GLDS, stream>>>(hs16, W1t, b1, gateb, hbcb, dtsec,
                                          MR, PROJD, HID, 34);
  // conv + SiLU + split (x8 vectorized)
  conv_silu<<<(BB * SS * (CONVD / 8)) / 256, 256, 0, stream>>>(hbcb, cw, X_lp, Bc, Cc);
  // dt softplus, then parallel per-chunk cumsum
  dtk<<<(BB * SS * HH) / 256, 256, 0, stream>>>(dtsec, dtb, alog, dtv);
  cumsum_scan<<<BB * HH, 256, 0, stream>>>(dtv, alog, cumA);
  // layout transposes for MFMA fragments (Xt overwrites W1t: dead)
  transpose_bf16<<<dim3(PP / 32, SS / 32, BB * HH), 256, 0, stream>>>(X_lp, Xt, SS, PP);
  transpose_bf16<<<dim3(NST / 32, SS / 32, BB), 256, 0, stream>>>(Bc, Btc, SS, NST);
  // SSD pass 1 (ybb overwrites hbcb: dead after conv)
  ssd1<<<dim3(HH, NC, BB), 256, 0, stream>>>(Cc, Bc, Btc, Xt, cumA, dtv, ybb, statesb);
  // inter-chunk recurrence, in place
  reck<<<(BB * HH * PP * NST) / 256, 256, 0, stream>>>(statesb, cumA);
  // SSD pass 2 (RMW on ybb)
  ssd2<<<dim3(HH, NC, BB), 256, 0, stream>>>(Cc, statesb, X_lp, cumA, Dv, ybb);
  // W2 transpose into region E (states dead after ssd2)
  transpose_w<<<dim3(HID / 32, INTER / 32), 256, 0, stream>>>(w2, W2t, INTER, HID);
  // gate + RMSNorm (xgn overwrites X_lp: dead after ssd2)
  gatenorm<<<MR, 256, 0, stream>>>(ybb, gateb, nw, xgn);
  // GEMM2: grid 32x8 = 256 (%8==0)
  gemm_bt<0><<<256, 256, GLDS, stream>>>(xgn, W2t, b2, out, nullptr, nullptr,
                                         MR, HID, INTER, 8);
}

// Round 6
// 594.742 us; speedup vs baseline: 1.2175x; 1.2175x over previous
//
#include <hip/hip_runtime.h>

// ---------------- dims ----------------
constexpr int HH    = 64;     // heads
constexpr int PP    = 64;     // head dim
constexpr int HID   = 2048;
constexpr int NST   = 128;    // state dim
constexpr int LCC   = 256;    // chunk len
constexpr int INTER = 4096;
constexpr int CONVD = 4352;
constexpr int PROJD = 8512;
constexpr int BB    = 4;
constexpr int SS    = 1024;
constexpr int NC    = 4;      // chunks
constexpr int MR    = BB * SS;      // 4096 rows
constexpr int NPAD1 = 8704;         // PROJD padded to 256

typedef unsigned short u16;
typedef __bf16 bf16x8_t __attribute__((ext_vector_type(8)));
typedef short short8 __attribute__((ext_vector_type(8)));
typedef float f32x4 __attribute__((ext_vector_type(4)));
typedef u16 u16x4 __attribute__((ext_vector_type(4)));

__device__ __forceinline__ float bf2f(u16 u) {
  union { unsigned int i; float f; } v; v.i = ((unsigned int)u) << 16; return v.f;
}
__device__ __forceinline__ u16 f2bf(float f) {
  union { float f; unsigned int i; } v; v.f = f;
  unsigned int r = v.i + 0x7FFFu + ((v.i >> 16) & 1u);
  return (u16)(r >> 16);
}
__device__ __forceinline__ f32x4 mfma16(short8 a, short8 b, f32x4 c) {
  union U { short8 s; bf16x8_t b; };
  U ua; ua.s = a; U ub; ub.s = b;
  return __builtin_amdgcn_mfma_f32_16x16x32_bf16(ua.b, ub.b, c, 0, 0, 0);
}
__device__ __forceinline__ float sigm(float x) { return 1.f / (1.f + __expf(-x)); }
__device__ __forceinline__ void gload16(const u16* g, u16* l) {
  __builtin_amdgcn_global_load_lds(
      (const __attribute__((address_space(1))) void*)g,
      (__attribute__((address_space(3))) void*)l, 16, 0, 0);
}

// ---------------- fp32 -> bf16 convert (hs) ------------------------------------
__global__ void f32_to_bf16(const float* __restrict__ in, u16* __restrict__ out) {
  int i = (blockIdx.x * 256 + threadIdx.x) * 8;
  float4 a = *(const float4*)&in[i];
  float4 b = *(const float4*)&in[i + 4];
  short8 v;
  v[0] = (short)f2bf(a.x); v[1] = (short)f2bf(a.y);
  v[2] = (short)f2bf(a.z); v[3] = (short)f2bf(a.w);
  v[4] = (short)f2bf(b.x); v[5] = (short)f2bf(b.y);
  v[6] = (short)f2bf(b.z); v[7] = (short)f2bf(b.w);
  *(short8*)&out[i] = v;
}

// ---------------- transpose f32 -> bf16 (weights), zero-pad extra out rows -----
__global__ void transpose_w(const float* __restrict__ in, u16* __restrict__ out,
                            int K_, int N_) {
  __shared__ float tile[32][33];
  int k0 = blockIdx.y * 32, n0 = blockIdx.x * 32, t = threadIdx.x;
#pragma unroll
  for (int i = 0; i < 4; ++i) {
    int flat = i * 256 + t; int kk = flat >> 5, nn = flat & 31;
    int n = n0 + nn;
    tile[kk][nn] = (n < N_) ? in[(size_t)(k0 + kk) * N_ + n] : 0.f;
  }
  __syncthreads();
#pragma unroll
  for (int i = 0; i < 4; ++i) {
    int flat = i * 256 + t; int nn = flat >> 5, kk = flat & 31;
    out[(size_t)(n0 + nn) * K_ + k0 + kk] = f2bf(tile[kk][nn]);
  }
}

// ---------------- generic bf16 transpose, batched: in [R][C] -> out [C][R] -----
__global__ void transpose_bf16(const u16* __restrict__ in, u16* __restrict__ out,
                               int R, int C) {
  int bt = blockIdx.z;
  const u16* ip = in + (size_t)bt * R * C;
  u16* op = out + (size_t)bt * R * C;
  __shared__ u16 tile[32][33];
  int r0 = blockIdx.y * 32, c0 = blockIdx.x * 32, t = threadIdx.x;
#pragma unroll
  for (int i = 0; i < 4; ++i) {
    int flat = i * 256 + t; int rr = flat >> 5, cc = flat & 31;
    tile[rr][cc] = ip[(size_t)(r0 + rr) * C + c0 + cc];
  }
  __syncthreads();
#pragma unroll
  for (int i = 0; i < 4; ++i) {
    int flat = i * 256 + t; int cc = flat >> 5, rr = flat & 31;
    op[(size_t)(c0 + cc) * R + r0 + rr] = tile[rr][cc];
  }
}

// ================= GEMM1: 256x256 tile, 8 waves, 8-phase counted-vmcnt =========
// m201-style: BK=64, 2 K-tiles/iter, dbuf LDS 128KB, acc 8x4/wave, T2 XOR swizzle.
// Split bf16 epilogue (gate / hbc / dt).
__global__ __launch_bounds__(512, 2) void gemm8p(
    const u16* __restrict__ A, const u16* __restrict__ Bt,
    const float* __restrict__ bias, u16* __restrict__ gateb,
    u16* __restrict__ hbcb, u16* __restrict__ dtsec,
    int Nreal, int K, int gx) {
  extern __shared__ u16 smem[];   // As[2][256*64] @0 ; Bs[2][256*64] @32768
  const int nwg = gridDim.x, bid = blockIdx.x;
  const int q = nwg >> 3;
  const int swz = (bid & 7) * q + (bid >> 3);
  const int bx = swz % gx, by = swz / gx;
  const int m0 = by * 256, n0 = bx * 256;
  const int t = threadIdx.x;
  const int w = t >> 6, lane = t & 63, lr = lane & 15, lhi = lane >> 4;
  const int wr = w >> 2, wc = w & 3;            // wave grid 2M x 4N
  const int strow = t >> 3;                     // 0..63
  const int schunk = (((t & 7) ^ ((t >> 3) & 7)) << 3);  // pre-swizzled src col
  const u16* gA = A + (size_t)(m0 + strow) * K + schunk;
  const u16* gB = Bt + (size_t)(n0 + strow) * K + schunk;
  const int swz_rd = (lr & 7) << 3;
  const int NT = K >> 6, NI = NT >> 1;

  auto stageA = [&](int kt, int h, int b) {
    const u16* src = gA + (size_t)(h * 128) * K + kt * 64;
    u16* dst = smem + b * 16384 + h * 8192 + w * 512;
    gload16(src, dst);
    gload16(src + (size_t)64 * K, dst + 4096);
  };
  auto stageB = [&](int kt, int h, int b) {
    const u16* src = gB + (size_t)(h * 128) * K + kt * 64;
    u16* dst = smem + 32768 + b * 16384 + h * 8192 + w * 512;
    gload16(src, dst);
    gload16(src + (size_t)64 * K, dst + 4096);
  };

#define LDA(buf, mi, ks) (*(const short8*)&smem[(buf)*16384 + (wr*128 + (mi)*16 + lr)*64 + (((ks)*32 + lhi*8) ^ swz_rd)])
#define LDB(buf, ni, ks) (*(const short8*)&smem[32768 + (buf)*16384 + (wc*64 + (ni)*16 + lr)*64 + (((ks)*32 + lhi*8) ^ swz_rd)])
#define PHASE_TOP()                                         \
  __builtin_amdgcn_s_barrier();                             \
  asm volatile("s_waitcnt lgkmcnt(0)" ::: "memory");        \
  __builtin_amdgcn_sched_barrier(0);                        \
  __builtin_amdgcn_s_setprio(1);
#define PHASE_BOT()                                         \
  __builtin_amdgcn_s_setprio(0);                            \
  __builtin_amdgcn_sched_barrier(0);                        \
  __builtin_amdgcn_s_barrier();
#define MFMA_NI(a, b)                                       \
  _Pragma("unroll") for (int mi = 0; mi < 8; ++mi) {        \
    acc[mi][a] = mfma16(af[mi], bf[a], acc[mi][a]);         \
    acc[mi][b] = mfma16(af[mi], bf[b], acc[mi][b]);         \
  }

  // prologue: tile0 (A0,A1,B0,B1) + tile1 A0 = 10 loads; retire tile0, keep 2.
  stageA(0, 0, 0); stageA(0, 1, 0); stageB(0, 0, 0); stageB(0, 1, 0);
  stageA(1, 0, 1);
  asm volatile("s_waitcnt vmcnt(2)" ::: "memory");
  __builtin_amdgcn_s_barrier();

  f32x4 acc[8][4] = {};
  short8 af[8], bf[4];
  for (int i = 0; i < NI; ++i) {
    const int T = 2 * i;
    const int t2 = (T + 2 < NT) ? T + 2 : NT - 1;
    const int t3 = (T + 3 < NT) ? T + 3 : NT - 1;
    // ---- K-tile T (buf0) ----
#pragma unroll
    for (int mi = 0; mi < 8; ++mi) af[mi] = LDA(0, mi, 0);
    bf[0] = LDB(0, 0, 0); bf[1] = LDB(0, 1, 0);
    stageA(T + 1, 1, 1);
    PHASE_TOP(); MFMA_NI(0, 1); PHASE_BOT();
    bf[2] = LDB(0, 2, 0); bf[3] = LDB(0, 3, 0);
    stageB(T + 1, 0, 1);
    PHASE_TOP(); MFMA_NI(2, 3); PHASE_BOT();
#pragma unroll
    for (int mi = 0; mi < 8; ++mi) af[mi] = LDA(0, mi, 1);
    bf[0] = LDB(0, 0, 1); bf[1] = LDB(0, 1, 1);
    stageB(T + 1, 1, 1);
    PHASE_TOP(); MFMA_NI(0, 1); PHASE_BOT();
    bf[2] = LDB(0, 2, 1); bf[3] = LDB(0, 3, 1);
    stageA(t2, 0, 0);
    asm volatile("s_waitcnt vmcnt(2)" ::: "memory");   // tile T+1 now resident
    PHASE_TOP(); MFMA_NI(2, 3); PHASE_BOT();
    // ---- K-tile T+1 (buf1) ----
#pragma unroll
    for (int mi = 0; mi < 8; ++mi) af[mi] = LDA(1, mi, 0);
    bf[0] = LDB(1, 0, 0); bf[1] = LDB(1, 1, 0);
    stageA(t2, 1, 0);
    PHASE_TOP(); MFMA_NI(0, 1); PHASE_BOT();
    bf[2] = LDB(1, 2, 0); bf[3] = LDB(1, 3, 0);
    stageB(t2, 0, 0);
    PHASE_TOP(); MFMA_NI(2, 3); PHASE_BOT();
#pragma unroll
    for (int mi = 0; mi < 8; ++mi) af[mi] = LDA(1, mi, 1);
    bf[0] = LDB(1, 0, 1); bf[1] = LDB(1, 1, 1);
    stageB(t2, 1, 0);
    PHASE_TOP(); MFMA_NI(0, 1); PHASE_BOT();
    bf[2] = LDB(1, 2, 1); bf[3] = LDB(1, 3, 1);
    stageA(t3, 0, 1);
    asm volatile("s_waitcnt vmcnt(2)" ::: "memory");   // tile T+2 now resident
    PHASE_TOP(); MFMA_NI(2, 3); PHASE_BOT();
  }
#undef LDA
#undef LDB
#undef PHASE_TOP
#undef PHASE_BOT
#undef MFMA_NI

#pragma unroll
  for (int ni = 0; ni < 4; ++ni) {
    int col = n0 + wc * 64 + ni * 16 + lr;
    if (col >= Nreal) continue;
    float bv = bias[col];
#pragma unroll
    for (int mi = 0; mi < 8; ++mi)
#pragma unroll
      for (int j = 0; j < 4; ++j) {
        int row = m0 + wr * 128 + mi * 16 + lhi * 4 + j;
        float v = acc[mi][ni][j] + bv;
        u16 o = f2bf(v);
        if (col < INTER)              gateb[(size_t)row * INTER + col] = o;
        else if (col < INTER + CONVD) hbcb[(size_t)row * CONVD + (col - INTER)] = o;
        else                          dtsec[(size_t)row * HH + (col - INTER - CONVD)] = o;
      }
  }
}

// ================= GEMM2: proven R4 kernel (128x128, 2-barrier, T2 swizzle) ====
__global__ __launch_bounds__(256) void gemm_r4(
    const u16* __restrict__ A, const u16* __restrict__ Bt,
    const float* __restrict__ bias, float* __restrict__ Cp,
    int Nreal, int K, int gx) {
  __shared__ __align__(16) u16 As[128 * 64];
  __shared__ __align__(16) u16 Bs[128 * 64];
  const int nwg = gridDim.x, bid = blockIdx.x;
  const int q = nwg >> 3;
  const int swz = (bid & 7) * q + (bid >> 3);
  const int bx = swz % gx, by = swz / gx;
  const int m0 = by * 128, n0 = bx * 128;
  const int t = threadIdx.x;
  const int w = t >> 6, lane = t & 63, lr = lane & 15, lhi = lane >> 4;
  const int wr = (w >> 1) * 64, wc = (w & 1) * 64;
  const int srow = t >> 3;
  const int sw_scol = (((t & 7) ^ ((t >> 3) & 7)) << 3);
  const u16* ga = A + (size_t)(m0 + srow) * K + sw_scol;
  const u16* gb = Bt + (size_t)(n0 + srow) * K + sw_scol;
  u16* la = As + w * 512;
  u16* lb = Bs + w * 512;
  const int swz_rd = (lr & 7) << 3;
  f32x4 acc[4][4] = {};
  for (int k0 = 0; k0 < K; k0 += 64) {
    __syncthreads();
#pragma unroll
    for (int j = 0; j < 4; ++j) {
      gload16(ga + (size_t)(j * 32) * K + k0, la + j * 2048);
      gload16(gb + (size_t)(j * 32) * K + k0, lb + j * 2048);
    }
    __syncthreads();
#pragma unroll
    for (int ks = 0; ks < 2; ++ks) {
      const int cs = (ks * 32 + lhi * 8) ^ swz_rd;
      short8 af[4], bfv[4];
#pragma unroll
      for (int mi = 0; mi < 4; ++mi)
        af[mi] = *(const short8*)&As[(wr + mi * 16 + lr) * 64 + cs];
#pragma unroll
      for (int ni = 0; ni < 4; ++ni)
        bfv[ni] = *(const short8*)&Bs[(wc + ni * 16 + lr) * 64 + cs];
#pragma unroll
      for (int mi = 0; mi < 4; ++mi)
#pragma unroll
        for (int ni = 0; ni < 4; ++ni)
          acc[mi][ni] = mfma16(af[mi], bfv[ni], acc[mi][ni]);
    }
  }
#pragma unroll
  for (int ni = 0; ni < 4; ++ni) {
    int col = n0 + wc + ni * 16 + lr;
    if (col >= Nreal) continue;
    float bv = bias[col];
#pragma unroll
    for (int mi = 0; mi < 4; ++mi)
#pragma unroll
      for (int j = 0; j < 4; ++j) {
        int row = m0 + wr + mi * 16 + lhi * 4 + j;
        Cp[(size_t)row * Nreal + col] = acc[mi][ni][j] + bv;
      }
  }
}

// ---------------- conv1d (K=4, causal) + SiLU + split, x8 vectorized -----------
__global__ __launch_bounds__(256) void conv_silu(
    const u16* __restrict__ hbcb, const float* __restrict__ convw,
    u16* __restrict__ X_lp, u16* __restrict__ Bc, u16* __restrict__ Cc) {
  int idx = blockIdx.x * 256 + threadIdx.x;  // < BB*SS*(CONVD/8)
  int c8 = idx % (CONVD / 8);
  int rest = idx / (CONVD / 8);
  int s = rest & (SS - 1);
  int b = rest >> 10;
  int ch = c8 * 8;
  short8 v[4];
#pragma unroll
  for (int k = 0; k < 4; ++k) {
    int ss = s - 3 + k;
    if (ss >= 0) v[k] = *(const short8*)&hbcb[(size_t)(b * SS + ss) * CONVD + ch];
    else         v[k] = short8{0, 0, 0, 0, 0, 0, 0, 0};
  }
  short8 o;
#pragma unroll
  for (int j = 0; j < 8; ++j) {
    float4 wj = *(const float4*)&convw[(ch + j) * 4];
    float a = bf2f((u16)v[0][j]) * wj.x + bf2f((u16)v[1][j]) * wj.y +
              bf2f((u16)v[2][j]) * wj.z + bf2f((u16)v[3][j]) * wj.w;
    o[j] = (short)f2bf(a * sigm(a));
  }
  if (ch < INTER)
    *(short8*)&X_lp[((size_t)(b * HH + (ch >> 6)) * SS + s) * PP + (ch & 63)] = o;
  else if (ch < INTER + NST)
    *(short8*)&Bc[((size_t)(b * SS + s)) * NST + (ch - INTER)] = o;
  else
    *(short8*)&Cc[((size_t)(b * SS + s)) * NST + (ch - INTER - NST)] = o;
}

// ---------------- dt: softplus(dt+bias) -> dtv [bh][s] -------------------------
__global__ void dtk(const u16* __restrict__ dtsec, const float* __restrict__ dtb,
                    const float* __restrict__ alog, float* __restrict__ dtv) {
  int idx = blockIdx.x * 256 + threadIdx.x;  // < BB*SS*HH
  int hh = idx & 63;
  int s = (idx >> 6) & (SS - 1);
  int b = idx >> 16;
  float x = bf2f(dtsec[(size_t)(b * SS + s) * HH + hh]) + dtb[hh];
  float sp = (x > 20.f) ? x : log1pf(__expf(x));
  dtv[(size_t)(b * HH + hh) * SS + s] = sp;
}

// ---------------- per-chunk inclusive cumsum of -exp(A_log)*dt (wave scan) -----
__global__ __launch_bounds__(256) void cumsum_scan(
    const float* __restrict__ dtv, const float* __restrict__ alog,
    float* __restrict__ cumA) {
  const int bh = blockIdx.x;
  const int h = bh & 63;
  const int t = threadIdx.x, w = t >> 6, lane = t & 63;
  const float na = -__expf(alog[h]);
  size_t base = (size_t)bh * SS + w * LCC;
  float4 v = *(const float4*)&dtv[base + lane * 4];
  float a0 = na * v.x;
  float s1 = a0 + na * v.y;
  float s2 = s1 + na * v.z;
  float tot = s2 + na * v.w;
  float run = tot;
#pragma unroll
  for (int off = 1; off < 64; off <<= 1) {
    float u = __shfl_up(run, off);
    if (lane >= off) run += u;
  }
  float excl = run - tot;
  float4 o; o.x = excl + a0; o.y = excl + s1; o.z = excl + s2; o.w = excl + tot;
  *(float4*)&cumA[base + lane * 4] = o;
}

// ---------------- SSD pass 1: Y_diag + chunk states ----------------------------
__global__ __launch_bounds__(256) void ssd1(
    const u16* __restrict__ Cc, const u16* __restrict__ Bc,
    const u16* __restrict__ Btc, const u16* __restrict__ Xt,
    const float* __restrict__ cumA, const float* __restrict__ dtv,
    u16* __restrict__ ybb, u16* __restrict__ statesb) {
  const int h = blockIdx.x, c = blockIdx.y, b = blockIdx.z;
  const int bh = b * HH + h, s0 = c * LCC;
  const int t = threadIdx.x, w = t >> 6, lane = t & 63, lr = lane & 15, lhi = lane >> 4;
  __shared__ float cumA_s[LCC], dtv_s[LCC], w_s[LCC];
  __shared__ __align__(16) u16 Mld[4][64 * 72];
  cumA_s[t] = cumA[(size_t)bh * SS + s0 + t];
  dtv_s[t] = dtv[(size_t)bh * SS + s0 + t];
  __syncthreads();
  w_s[t] = dtv_s[t] * __expf(cumA_s[LCC - 1] - cumA_s[t]);
  __syncthreads();

  f32x4 Yacc[4][4] = {};
  u16* Mw = &Mld[w][0];
  for (int st = 0; st <= w; ++st) {
    f32x4 G[4][4] = {};
#pragma unroll
    for (int ks = 0; ks < 4; ++ks) {
      short8 cf[4], bfr[4];
#pragma unroll
      for (int mi = 0; mi < 4; ++mi)
        cf[mi] = *(const short8*)&Cc[((size_t)(b * SS + s0 + w * 64 + mi * 16 + lr)) * NST + ks * 32 + lhi * 8];
#pragma unroll
      for (int ni = 0; ni < 4; ++ni)
        bfr[ni] = *(const short8*)&Bc[((size_t)(b * SS + s0 + st * 64 + ni * 16 + lr)) * NST + ks * 32 + lhi * 8];
#pragma unroll
      for (int mi = 0; mi < 4; ++mi)
#pragma unroll
        for (int ni = 0; ni < 4; ++ni)
          G[mi][ni] = mfma16(cf[mi], bfr[ni], G[mi][ni]);
    }
#pragma unroll
    for (int mi = 0; mi < 4; ++mi)
#pragma unroll
      for (int ni = 0; ni < 4; ++ni) {
        int sloc = st * 64 + ni * 16 + lr;
        float ds = dtv_s[sloc];
#pragma unroll
        for (int j = 0; j < 4; ++j) {
          int l = w * 64 + mi * 16 + lhi * 4 + j;
          float v = (sloc <= l) ? G[mi][ni][j] * __expf(cumA_s[l] - cumA_s[sloc]) * ds : 0.f;
          Mw[(mi * 16 + lhi * 4 + j) * 72 + ni * 16 + lr] = f2bf(v);
        }
      }
#pragma unroll
    for (int kh = 0; kh < 2; ++kh) {
      short8 xf[4];
#pragma unroll
      for (int ni = 0; ni < 4; ++ni)
        xf[ni] = *(const short8*)&Xt[((size_t)bh * PP + ni * 16 + lr) * SS + s0 + st * 64 + kh * 32 + lhi * 8];
#pragma unroll
      for (int mi = 0; mi < 4; ++mi) {
        short8 mf = *(const short8*)&Mw[(mi * 16 + lr) * 72 + kh * 32 + lhi * 8];
#pragma unroll
        for (int ni = 0; ni < 4; ++ni)
          Yacc[mi][ni] = mfma16(mf, xf[ni], Yacc[mi][ni]);
      }
    }
  }
#pragma unroll
  for (int mi = 0; mi < 4; ++mi)
#pragma unroll
    for (int ni = 0; ni < 4; ++ni)
#pragma unroll
      for (int j = 0; j < 4; ++j) {
        int l = w * 64 + mi * 16 + lhi * 4 + j;
        int p = ni * 16 + lr;
        ybb[((size_t)(b * SS + s0 + l)) * INTER + h * PP + p] = f2bf(Yacc[mi][ni][j]);
      }
  f32x4 Sacc[4][2] = {};
  for (int ks = 0; ks < 8; ++ks) {
    f32x4 w0 = *(const f32x4*)&w_s[ks * 32 + lhi * 8];
    f32x4 w1 = *(const f32x4*)&w_s[ks * 32 + lhi * 8 + 4];
    short8 bfr[2];
#pragma unroll
    for (int nj = 0; nj < 2; ++nj) {
      short8 br = *(const short8*)&Btc[((size_t)b * NST + w * 32 + nj * 16 + lr) * SS + s0 + ks * 32 + lhi * 8];
      short8 bs;
      bs[0] = (short)f2bf(bf2f((u16)br[0]) * w0[0]);
      bs[1] = (short)f2bf(bf2f((u16)br[1]) * w0[1]);
      bs[2] = (short)f2bf(bf2f((u16)br[2]) * w0[2]);
      bs[3] = (short)f2bf(bf2f((u16)br[3]) * w0[3]);
      bs[4] = (short)f2bf(bf2f((u16)br[4]) * w1[0]);
      bs[5] = (short)f2bf(bf2f((u16)br[5]) * w1[1]);
      bs[6] = (short)f2bf(bf2f((u16)br[6]) * w1[2]);
      bs[7] = (short)f2bf(bf2f((u16)br[7]) * w1[3]);
      bfr[nj] = bs;
    }
#pragma unroll
    for (int mi = 0; mi < 4; ++mi) {
      short8 af = *(const short8*)&Xt[((size_t)bh * PP + mi * 16 + lr) * SS + s0 + ks * 32 + lhi * 8];
#pragma unroll
      for (int nj = 0; nj < 2; ++nj)
        Sacc[mi][nj] = mfma16(af, bfr[nj], Sacc[mi][nj]);
    }
  }
#pragma unroll
  for (int mi = 0; mi < 4; ++mi)
#pragma unroll
    for (int nj = 0; nj < 2; ++nj)
#pragma unroll
      for (int j = 0; j < 4; ++j) {
        int p = mi * 16 + lhi * 4 + j;
        int n = w * 32 + nj * 16 + lr;
        statesb[((((size_t)b * NC + c) * HH + h) * PP + p) * NST + n] = f2bf(Sacc[mi][nj][j]);
      }
}

// ---------------- inter-chunk recurrence (IN PLACE: states -> prev) ------------
__global__ void reck(u16* __restrict__ statesb, const float* __restrict__ cumA) {
  int idx = blockIdx.x * 256 + threadIdx.x;  // < BB*HH*PP*NST
  int n = idx & 127, p = (idx >> 7) & 63, bh = idx >> 13;
  int b = bh >> 6, h = bh & 63;
  float prev = 0.f;
#pragma unroll
  for (int c2 = 0; c2 < NC; ++c2) {
    size_t si = ((((size_t)b * NC + c2) * HH + h) * PP + p) * NST + n;
    float s = bf2f(statesb[si]);           // read BEFORE overwrite
    statesb[si] = f2bf(prev);
    float tot = cumA[(size_t)bh * SS + c2 * LCC + (LCC - 1)];
    prev = prev * __expf(tot) + s;
  }
}

// ---------------- SSD pass 2: Y_off + D residual (y in bf16, RMW) --------------
__global__ __launch_bounds__(256) void ssd2(
    const u16* __restrict__ Cc, const u16* __restrict__ prevb,
    const u16* __restrict__ X_lp, const float* __restrict__ cumA,
    const float* __restrict__ Dv, u16* __restrict__ ybb) {
  const int h = blockIdx.x, c = blockIdx.y, b = blockIdx.z;
  const int bh = b * HH + h, s0 = c * LCC;
  const int t = threadIdx.x, w = t >> 6, lane = t & 63, lr = lane & 15, lhi = lane >> 4;
  __shared__ float cumA_s[LCC];
  cumA_s[t] = cumA[(size_t)bh * SS + s0 + t];
  __syncthreads();
  f32x4 acc[4][4] = {};
  const size_t stbase = (((size_t)b * NC + c) * HH + h) * PP;
#pragma unroll
  for (int ks = 0; ks < 4; ++ks) {
    short8 sf[4];
#pragma unroll
    for (int pj = 0; pj < 4; ++pj)
      sf[pj] = *(const short8*)&prevb[(stbase + pj * 16 + lr) * NST + ks * 32 + lhi * 8];
#pragma unroll
    for (int mi = 0; mi < 4; ++mi) {
      short8 cf = *(const short8*)&Cc[((size_t)(b * SS + s0 + w * 64 + mi * 16 + lr)) * NST + ks * 32 + lhi * 8];
#pragma unroll
      for (int pj = 0; pj < 4; ++pj)
        acc[mi][pj] = mfma16(cf, sf[pj], acc[mi][pj]);
    }
  }
  float Dh = Dv[h];
#pragma unroll
  for (int mi = 0; mi < 4; ++mi)
#pragma unroll
    for (int pj = 0; pj < 4; ++pj)
#pragma unroll
      for (int j = 0; j < 4; ++j) {
        int l = w * 64 + mi * 16 + lhi * 4 + j;
        int p = pj * 16 + lr;
        size_t yi = ((size_t)(b * SS + s0 + l)) * INTER + h * PP + p;
        float xv = bf2f(X_lp[((size_t)bh * SS + s0 + l) * PP + p]);
        float cur = bf2f(ybb[yi]);
        ybb[yi] = f2bf(cur + acc[mi][pj][j] * __expf(cumA_s[l]) + Dh * xv);
      }
}

// ---------------- gate (SiLU) + RMSNorm -> bf16 --------------------------------
__global__ __launch_bounds__(256) void gatenorm(
    const u16* __restrict__ ybb, const u16* __restrict__ gateb,
    const float* __restrict__ nw, u16* __restrict__ xgn) {
  const int r = blockIdx.x, t = threadIdx.x;
  const int w = t >> 6, lane = t & 63;
  float xg[16];
  float s2 = 0.f;
#pragma unroll
  for (int i = 0; i < 2; ++i) {
    int col = (i * 256 + t) * 8;
    short8 yv = *(const short8*)&ybb[(size_t)r * INTER + col];
    short8 gv = *(const short8*)&gateb[(size_t)r * INTER + col];
#pragma unroll
    for (int j = 0; j < 8; ++j) {
      float g = bf2f((u16)gv[j]);
      float o = bf2f((u16)yv[j]) * g * sigm(g);
      xg[i * 8 + j] = o;
      s2 += o * o;
    }
  }
#pragma unroll
  for (int off = 32; off > 0; off >>= 1) s2 += __shfl_down(s2, off);
  __shared__ float red[4];
  if (lane == 0) red[w] = s2;
  __syncthreads();
  float rstd = rsqrtf((red[0] + red[1] + red[2] + red[3]) * (1.f / INTER) + 1e-5f);
#pragma unroll
  for (int i = 0; i < 2; ++i) {
    int col = (i * 256 + t) * 8;
    short8 o;
#pragma unroll
    for (int j = 0; j < 8; ++j)
      o[j] = (short)f2bf(xg[i * 8 + j] * rstd * nw[col + j]);
    *(short8*)&xgn[(size_t)r * INTER + col] = o;
  }
}

// ---------------- launch -------------------------------------------------------
extern "C" void kernel_launch(void* const* d_in, const int* in_sizes, int n_in,
                              void* d_out, int out_size, void* d_ws, size_t ws_size,
                              hipStream_t stream) {
  const float* hs   = (const float*)d_in[0];
  const float* w1   = (const float*)d_in[1];
  const float* b1   = (const float*)d_in[2];
  const float* cw   = (const float*)d_in[3];
  const float* dtb  = (const float*)d_in[4];
  const float* alog = (const float*)d_in[5];
  const float* Dv   = (const float*)d_in[6];
  const float* nw   = (const float*)d_in[7];
  const float* w2   = (const float*)d_in[8];
  const float* b2   = (const float*)d_in[9];
  float* out = (float*)d_out;

  char* ws = (char*)d_ws;
  size_t off = 0;
  auto alloc = [&](size_t bytes) -> char* {
    char* p = ws + off;
    off += (bytes + 255) & ~(size_t)255;
    return p;
  };
  // region A: W1t (35.7MB) -> Xt (33.6MB) after GEMM1
  char* regA = alloc((size_t)NPAD1 * HID * 2);
  u16* W1t = (u16*)regA;
  u16* Xt  = (u16*)regA;
  // region B: gate (bf16) [GEMM1 .. gatenorm]
  u16* gateb = (u16*)alloc((size_t)MR * INTER * 2);
  // region C: hbc (35.7MB) -> y bf16 (33.6MB) after conv
  char* regC = alloc((size_t)MR * CONVD * 2);
  u16* hbcb = (u16*)regC;
  u16* ybb  = (u16*)regC;
  // region D: X_lp -> xgn after ssd2
  char* regD = alloc((size_t)BB * HH * SS * PP * 2);
  u16* X_lp = (u16*)regD;
  u16* xgn  = (u16*)regD;
  // region E: states bf16 (in-place -> prev) -> W2t after ssd2
  char* regE = alloc((size_t)BB * NC * HH * PP * NST * 2);
  u16* statesb = (u16*)regE;
  u16* W2t     = (u16*)regE;
  // small buffers
  u16*   hs16  = (u16*)alloc((size_t)MR * HID * 2);
  u16*   dtsec = (u16*)alloc((size_t)MR * HH * 2);
  u16*   Bc    = (u16*)alloc((size_t)BB * SS * NST * 2);
  u16*   Cc    = (u16*)alloc((size_t)BB * SS * NST * 2);
  u16*   Btc   = (u16*)alloc((size_t)BB * NST * SS * 2);
  float* dtv   = (float*)alloc((size_t)BB * HH * SS * 4);
  float* cumA  = (float*)alloc((size_t)BB * HH * SS * 4);

  if (off > ws_size) return;  // graceful fail -> diagnostic absmax

  hipFuncSetAttribute((const void*)gemm8p,
                      hipFuncAttributeMaxDynamicSharedMemorySize, 131072);

  // hs fp32 -> bf16
  f32_to_bf16<<<(MR * HID) / (256 * 8), 256, 0, stream>>>(hs, hs16);
  // W1 transpose (fp32 -> bf16, padded rows zeroed)
  transpose_w<<<dim3(NPAD1 / 32, HID / 32), 256, 0, stream>>>(w1, W1t, HID, PROJD);
  // GEMM1: 256^2 8-phase; grid 34x16 = 544 (%8==0)
  gemm8p<<<544, 512, 131072, stream>>>(hs16, W1t, b1, gateb, hbcb, dtsec,
                                       PROJD, HID, 34);
  // conv + SiLU + split (x8 vectorized)
  conv_silu<<<(BB * SS * (CONVD / 8)) / 256, 256, 0, stream>>>(hbcb, cw, X_lp, Bc, Cc);
  // dt softplus, then parallel per-chunk cumsum
  dtk<<<(BB * SS * HH) / 256, 256, 0, stream>>>(dtsec, dtb, alog, dtv);
  cumsum_scan<<<BB * HH, 256, 0, stream>>>(dtv, alog, cumA);
  // layout transposes for MFMA fragments (Xt overwrites W1t: dead)
  transpose_bf16<<<dim3(PP / 32, SS / 32, BB * HH), 256, 0, stream>>>(X_lp, Xt, SS, PP);
  transpose_bf16<<<dim3(NST / 32, SS / 32, BB), 256, 0, stream>>>(Bc, Btc, SS, NST);
  // SSD pass 1 (ybb overwrites hbcb: dead after conv)
  ssd1<<<dim3(HH, NC, BB), 256, 0, stream>>>(Cc, Bc, Btc, Xt, cumA, dtv, ybb, statesb);
  // inter-chunk recurrence, in place
  reck<<<(BB * HH * PP * NST) / 256, 256, 0, stream>>>(statesb, cumA);
  // SSD pass 2 (RMW on ybb)
  ssd2<<<dim3(HH, NC, BB), 256, 0, stream>>>(Cc, statesb, X_lp, cumA, Dv, ybb);
  // W2 transpose into region E (states dead after ssd2)
  transpose_w<<<dim3(HID / 32, INTER / 32), 256, 0, stream>>>(w2, W2t, INTER, HID);
  // gate + RMSNorm (xgn overwrites X_lp: dead after ssd2)
  gatenorm<<<MR, 256, 0, stream>>>(ybb, gateb, nw, xgn);
  // GEMM2: proven R4 kernel; grid 16*32 = 512 (%8==0)
  gemm_r4<<<512, 256, 0, stream>>>(xgn, W2t, b2, out, HID, INTER, 16);
}